// Round 11
// baseline (73.166 us; speedup 1.0000x reference)
//
#include <hip/hip_runtime.h>

#define IMG_H 1024
#define IMG_W 1024
#define IMG_C 3

// Interior: x in [2,1017], 2 px per thread, 508 strips per row.
#define SPR 508
#define INT_ROWS 1019                           // y = 2..1020
#define N_STRIPS (IMG_C * INT_ROWS * SPR)       // 1,552,956
#define NB_INT ((N_STRIPS + 255) / 256)         // 6067
#define BND_PER_C (5 * 1024 + INT_ROWS * 8)     // 13,272
#define N_BND (IMG_C * BND_PER_C)               // 39,816
#define NB_BND ((N_BND + 255) / 256)            // 156

// ===== packed f16x2 machinery (bench-verified rounds 6-10, absmax 0.0078125) =====
typedef _Float16 h2 __attribute__((ext_vector_type(2)));

__device__ __forceinline__ h2 h2min(h2 a, h2 b) { return __builtin_elementwise_min(a, b); }
__device__ __forceinline__ h2 h2max(h2 a, h2 b) { return __builtin_elementwise_max(a, b); }
__device__ __forceinline__ void CEh(h2& a, h2& b) { h2 t = h2min(a, b); b = h2max(a, b); a = t; }

__device__ __forceinline__ h2 pkrtz(float a, float b) {
    auto v = __builtin_amdgcn_cvt_pkrtz(a, b);   // v_cvt_pkrtz_f16_f32
    h2 r;
    __builtin_memcpy(&r, &v, sizeof(r));
    return r;
}

__device__ __forceinline__ h2 pk_hilo(h2 a, h2 b) { h2 r; r.x = a.y; r.y = b.x; return r; } // {a.hi, b.lo}

// 9-CE optimal sorting network for 5 (verified round 6+).
__device__ __forceinline__ void sort5h(h2* a) {
    CEh(a[0], a[1]); CEh(a[3], a[4]); CEh(a[2], a[4]); CEh(a[2], a[3]);
    CEh(a[0], a[3]); CEh(a[0], a[2]); CEh(a[1], a[4]); CEh(a[1], a[3]);
    CEh(a[1], a[2]);
}

__device__ __forceinline__ void merge22h(const h2* A, const h2* B, h2* out) {
    h2 e0 = h2min(A[0], B[0]), e1 = h2max(A[0], B[0]);
    h2 o0 = h2min(A[1], B[1]), o1 = h2max(A[1], B[1]);
    out[0] = e0;
    out[1] = h2min(o0, e1); out[2] = h2max(o0, e1);
    out[3] = o1;
}

__device__ __forceinline__ void merge33h(const h2* A, const h2* B, h2* out) {
    h2 Ae[2] = {A[0], A[2]}, Be[2] = {B[0], B[2]};
    h2 E[4];
    merge22h(Ae, Be, E);
    h2 O0 = h2min(A[1], B[1]), O1 = h2max(A[1], B[1]);
    out[0] = E[0];
    out[1] = h2min(O0, E[1]); out[2] = h2max(O0, E[1]);
    out[3] = h2min(O1, E[2]); out[4] = h2max(O1, E[2]);
    out[5] = E[3];
}

__device__ __forceinline__ void merge55h(const h2* A, const h2* B, h2* out) {
    h2 Ae[3] = {A[0], A[2], A[4]}, Be[3] = {B[0], B[2], B[4]};
    h2 E[6];
    merge33h(Ae, Be, E);
    h2 Ao[2] = {A[1], A[3]}, Bo[2] = {B[1], B[3]};
    h2 O[4];
    merge22h(Ao, Bo, O);
    out[0] = E[0];
    out[1] = h2min(O[0], E[1]); out[2] = h2max(O[0], E[1]);
    out[3] = h2min(O[1], E[2]); out[4] = h2max(O[1], E[2]);
    out[5] = h2min(O[2], E[3]); out[6] = h2max(O[2], E[3]);
    out[7] = h2min(O[3], E[4]); out[8] = h2max(O[3], E[4]);
    out[9] = E[5];
}

// Pruned merge of two sorted-5s: outputs 3..6 only (bench-verified round 10).
struct Sub4 { h2 r3, r4, r5, r6; };
__device__ __forceinline__ Sub4 sub55(const h2* A, const h2* B) {
    h2 e1  = h2max(A[1], B[1]);
    h2 o0  = h2min(A[3], B[3]);
    h2 P1  = h2min(o0, e1);
    h2 P2  = h2max(o0, e1);
    h2 e1b = h2max(A[0], B[0]);
    h2 o0b = h2min(A[4], B[4]);
    h2 E1b = h2min(o0b, e1b);
    h2 E2b = h2max(o0b, e1b);
    h2 O0b = h2min(A[2], B[2]);
    h2 O1b = h2max(A[2], B[2]);
    h2 E2  = h2max(O0b, E1b);
    h2 E3  = h2min(O1b, E2b);
    Sub4 s;
    s.r3 = h2min(P1, E2); s.r4 = h2max(P1, E2);
    s.r5 = h2min(P2, E3); s.r6 = h2max(P2, E3);
    return s;
}

// ranks 7..12 (0-idx) of merge(A10,B10) (bench-verified round 10).
__device__ __forceinline__ void mid6_of_20(const h2* A, const h2* B, h2* mid) {
    h2 Ae[5] = {A[0], A[2], A[4], A[6], A[8]}, Be[5] = {B[0], B[2], B[4], B[6], B[8]};
    h2 Ao[5] = {A[1], A[3], A[5], A[7], A[9]}, Bo[5] = {B[1], B[3], B[5], B[7], B[9]};
    Sub4 E = sub55(Ae, Be);
    Sub4 O = sub55(Ao, Bo);
    mid[0] = h2min(O.r3, E.r4); mid[1] = h2max(O.r3, E.r4);
    mid[2] = h2min(O.r4, E.r5); mid[3] = h2max(O.r4, E.r5);
    mid[4] = h2min(O.r5, E.r6); mid[5] = h2max(O.r5, E.r6);
}

// median25 = rank-5 (0-idx) of mid6 ∪ c5 via min-of-max selection (verified round 10).
__device__ __forceinline__ h2 sel_median(const h2* mid, const h2* c5) {
    h2 m0 = h2max(mid[0], c5[4]);
    h2 m1 = h2max(mid[1], c5[3]);
    h2 m2 = h2max(mid[2], c5[2]);
    h2 m3 = h2max(mid[3], c5[1]);
    h2 m4 = h2max(mid[4], c5[0]);
    return h2min(h2min(h2min(m0, m1), h2min(m2, m3)), h2min(m4, mid[5]));
}

__global__ __launch_bounds__(256) void median5_kernel(const float* __restrict__ img,
                                                      float* __restrict__ out) {
    const float INF = __builtin_inff();

    if (blockIdx.x >= NB_BND) {
        // ===== interior: 2 px/thread, packed f16, high occupancy (R1 regime) =====
        int gid = (blockIdx.x - NB_BND) * 256 + threadIdx.x;
        if (gid >= N_STRIPS) return;
        int xs = gid % SPR;
        int t = gid / SPR;
        int y = 2 + t % INT_ROWS;
        int c = t / INT_ROWS;
        int x0 = 2 + 2 * xs;

        const float* p = img + (size_t)c * IMG_H * IMG_W + (size_t)(y - 2) * IMG_W + (x0 - 2);

        // batch 10 loads: cols k0..k7 (k = x0-2+idx) over rows y-2..y+2
        float4 LA[5], LB[5];
#pragma unroll
        for (int r = 0; r < 5; ++r) {
            LA[r] = *(const float4*)(p + r * IMG_W);       // k0..k3
            LB[r] = *(const float4*)(p + r * IMG_W + 4);   // k4..k7 (k6,k7 unused)
        }

        // packed columns: P0={k0,k1}, P1={k2,k3}, P2={k4,k5}
        h2 P0[5], P1[5], P2[5];
#pragma unroll
        for (int r = 0; r < 5; ++r) {
            P0[r] = pkrtz(LA[r].x, LA[r].y);
            P1[r] = pkrtz(LA[r].z, LA[r].w);
            P2[r] = pkrtz(LB[r].x, LB[r].y);
        }
        sort5h(P0); sort5h(P1); sort5h(P2);

        // px0 (cols k0..k4): pairs (k0,k1),(k2,k3), single k4
        // px1 (cols k1..k5): pairs (k1,k2),(k3,k4), single k5
        h2 Y1[5], Y2[5];
#pragma unroll
        for (int r = 0; r < 5; ++r) {
            Y1[r] = pk_hilo(P0[r], P1[r]);   // {k1, k2} sorted
            Y2[r] = pk_hilo(P1[r], P2[r]);   // {k3, k4} sorted
        }
        h2 MA[10], MB[10];
        merge55h(P0, Y1, MA);                // {M(k0,k1), M(k1,k2)}
        merge55h(P1, Y2, MB);                // {M(k2,k3), M(k3,k4)}

        h2 mid[6];
        mid6_of_20(MA, MB, mid);             // {mid20(px0), mid20(px1)}
        h2 F = sel_median(mid, P2);          // {px0, px1}

        float* po = out + (size_t)c * IMG_H * IMG_W + (size_t)y * IMG_W + x0;
        *(float2*)po = make_float2((float)F.x, (float)F.y);   // 8B aligned
    } else {
        // ===== boundary frame FIRST: exact fp32 bitonic-32 (verified rounds 1-10) =====
        int gid = blockIdx.x * 256 + threadIdx.x;
        if (gid >= N_BND) return;
        int c = gid / BND_PER_C;
        int b = gid % BND_PER_C;
        int y, x;
        if (b < 2048) {                 // rows 0,1
            y = b >> 10; x = b & 1023;
        } else if (b < 5120) {          // rows 1021..1023
            int t2 = b - 2048;
            y = 1021 + (t2 >> 10); x = t2 & 1023;
        } else {                        // rows 2..1020, cols {0,1} ∪ {1018..1023}
            int t2 = b - 5120;
            y = 2 + (t2 >> 3);
            int m = t2 & 7;
            x = (m < 2) ? m : (1016 + m);
        }

        const float* p = img + (size_t)c * IMG_H * IMG_W;
        float v[32];
#pragma unroll
        for (int i = 25; i < 32; ++i) v[i] = INF;
#pragma unroll
        for (int dy = -2; dy <= 2; ++dy) {
#pragma unroll
            for (int dx = -2; dx <= 2; ++dx) {
                int yy = y + dy;
                int xx = x + dx;
                bool valid = (yy >= 0) && (yy <= IMG_H - 2) && (xx >= 0) && (xx <= IMG_W - 2);
                int yc = min(max(yy, 0), IMG_H - 1);
                int xc = min(max(xx, 0), IMG_W - 1);
                float val = p[yc * IMG_W + xc];
                v[(dy + 2) * 5 + (dx + 2)] = valid ? val : INF;
            }
        }
#pragma unroll
        for (int k = 2; k <= 32; k <<= 1) {
#pragma unroll
            for (int j = k >> 1; j > 0; j >>= 1) {
#pragma unroll
                for (int i = 0; i < 32; ++i) {
                    int l = i ^ j;
                    if (l > i) {
                        bool up = ((i & k) == 0);
                        float a = v[i];
                        float b2 = v[l];
                        float mn = fminf(a, b2);
                        float mx = fmaxf(a, b2);
                        v[i] = up ? mn : mx;
                        v[l] = up ? mx : mn;
                    }
                }
            }
        }
        int ny = min(y + 2, IMG_H - 2) - max(y - 2, 0) + 1;
        int nx = min(x + 2, IMG_W - 2) - max(x - 2, 0) + 1;
        int n = ny * nx;
        int ilo = (n - 1) >> 1;
        int ihi = n >> 1;
        float lo = 0.0f, hi = 0.0f;
#pragma unroll
        for (int i = 0; i < 13; ++i) {
            if (i == ilo) lo = v[i];
            if (i == ihi) hi = v[i];
        }
        out[(size_t)c * IMG_H * IMG_W + (size_t)y * IMG_W + x] = 0.5f * (lo + hi);
    }
}

extern "C" void kernel_launch(void* const* d_in, const int* in_sizes, int n_in,
                              void* d_out, int out_size, void* d_ws, size_t ws_size,
                              hipStream_t stream) {
    const float* img = (const float*)d_in[0];
    float* out = (float*)d_out;
    dim3 block(256);
    dim3 grid(NB_BND + NB_INT);
    median5_kernel<<<grid, block, 0, stream>>>(img, out);
}

// Round 12
// 67.893 us; speedup vs baseline: 1.0777x; 1.0777x over previous
//
#include <hip/hip_runtime.h>

#define IMG_H 1024
#define IMG_W 1024
#define IMG_C 3

// Interior: x in [2,1017], 8 px wide x 2 rows per thread, 127 strips per row-pair.
#define SPR 127
#define ROWPAIRS 510                            // y0 = min(2+2*rp, 1019); rows y0, y0+1
#define N_STRIPS (IMG_C * ROWPAIRS * SPR)       // 194,310
#define NB_INT ((N_STRIPS + 255) / 256)         // 760
#define INT_ROWS 1019
#define BND_PER_C (5 * 1024 + INT_ROWS * 8)     // 13,272
#define N_BND (IMG_C * BND_PER_C)               // 39,816
#define NB_BND ((N_BND + 255) / 256)            // 156

// ===== packed f16x2 compare-exchange machinery (bench-verified rounds 6-11) =====
typedef _Float16 h2 __attribute__((ext_vector_type(2)));

__device__ __forceinline__ h2 h2min(h2 a, h2 b) { return __builtin_elementwise_min(a, b); }
__device__ __forceinline__ h2 h2max(h2 a, h2 b) { return __builtin_elementwise_max(a, b); }
__device__ __forceinline__ void CEh(h2& a, h2& b) { h2 t = h2min(a, b); b = h2max(a, b); a = t; }

__device__ __forceinline__ h2 pkrtz(float a, float b) {
    auto v = __builtin_amdgcn_cvt_pkrtz(a, b);   // v_cvt_pkrtz_f16_f32
    h2 r;
    __builtin_memcpy(&r, &v, sizeof(r));
    return r;
}

__device__ __forceinline__ void merge22h(const h2* A, const h2* B, h2* out) {
    h2 e0 = h2min(A[0], B[0]), e1 = h2max(A[0], B[0]);
    h2 o0 = h2min(A[1], B[1]), o1 = h2max(A[1], B[1]);
    out[0] = e0;
    out[1] = h2min(o0, e1); out[2] = h2max(o0, e1);
    out[3] = o1;
}

__device__ __forceinline__ void merge33h(const h2* A, const h2* B, h2* out) {
    h2 Ae[2] = {A[0], A[2]}, Be[2] = {B[0], B[2]};
    h2 E[4];
    merge22h(Ae, Be, E);
    h2 O0 = h2min(A[1], B[1]), O1 = h2max(A[1], B[1]);
    out[0] = E[0];
    out[1] = h2min(O0, E[1]); out[2] = h2max(O0, E[1]);
    out[3] = h2min(O1, E[2]); out[4] = h2max(O1, E[2]);
    out[5] = E[3];
}

__device__ __forceinline__ void merge55h(const h2* A, const h2* B, h2* out) {
    h2 Ae[3] = {A[0], A[2], A[4]}, Be[3] = {B[0], B[2], B[4]};
    h2 E[6];
    merge33h(Ae, Be, E);
    h2 Ao[2] = {A[1], A[3]}, Bo[2] = {B[1], B[3]};
    h2 O[4];
    merge22h(Ao, Bo, O);
    out[0] = E[0];
    out[1] = h2min(O[0], E[1]); out[2] = h2max(O[0], E[1]);
    out[3] = h2min(O[1], E[2]); out[4] = h2max(O[1], E[2]);
    out[5] = h2min(O[2], E[3]); out[6] = h2max(O[2], E[3]);
    out[7] = h2min(O[3], E[4]); out[8] = h2max(O[3], E[4]);
    out[9] = E[5];
}

__device__ __forceinline__ void merge1010_midh(const h2* A, const h2* B, h2* mid) {
    h2 Ae[5] = {A[0], A[2], A[4], A[6], A[8]}, Be[5] = {B[0], B[2], B[4], B[6], B[8]};
    h2 E[10];
    merge55h(Ae, Be, E);
    h2 Ao[5] = {A[1], A[3], A[5], A[7], A[9]}, Bo[5] = {B[1], B[3], B[5], B[7], B[9]};
    h2 O[10];
    merge55h(Ao, Bo, O);
    mid[0] = h2min(O[3], E[4]); mid[1] = h2max(O[3], E[4]);
    mid[2] = h2min(O[4], E[5]); mid[3] = h2max(O[4], E[5]);
    mid[4] = h2min(O[5], E[6]); mid[5] = h2max(O[5], E[6]);
}

__device__ __forceinline__ h2 final_medianh(const h2* mid, const h2* c5) {
    const _Float16 hinf = (_Float16)__builtin_inff();
    h2 INF2 = {hinf, hinf};
    h2 Ae[3] = {mid[0], mid[2], mid[4]}, Be[3] = {c5[0], c5[2], c5[4]};
    h2 E[6];
    merge33h(Ae, Be, E);
    h2 Ao[3] = {mid[1], mid[3], mid[5]}, Bo[3] = {c5[1], c5[3], INF2};
    h2 O[6];
    merge33h(Ao, Bo, O);
    return h2min(O[2], E[3]);
}

// Whole-strip median network for one window row (bench-verified rounds 6-7).
__device__ __forceinline__ void strip_medians(const h2 Q[8][5], float* po) {
    h2 MA[10], MB[10], MC[10], MD[10];
    merge55h(Q[0], Q[1], MA);   // {M0, M2}
    merge55h(Q[2], Q[3], MB);   // {M1, M3}
    merge55h(Q[4], Q[5], MC);   // {M2, M4}
    merge55h(Q[6], Q[7], MD);   // {M3, M5}

    h2 midA[6], midB[6], midC[6];
    merge1010_midh(MA, MB, midA);   // {mid01, mid23}
    merge1010_midh(MB, MC, midB);   // {mid12, mid34}
    merge1010_midh(MC, MD, midC);   // {mid23, mid45}

    h2 F1 = final_medianh(midA, Q[4]);   // {px0, px4}
    h2 F2 = final_medianh(midB, Q[1]);   // {px1, px5}
    h2 F3 = final_medianh(midB, Q[6]);   // {px2, px6}
    h2 F4 = final_medianh(midC, Q[3]);   // {px3, px7}

    float2* po2 = (float2*)po;           // 8B aligned
    po2[0] = make_float2((float)F1.x, (float)F2.x);
    po2[1] = make_float2((float)F3.x, (float)F4.x);
    po2[2] = make_float2((float)F1.y, (float)F2.y);
    po2[3] = make_float2((float)F3.y, (float)F4.y);
}

// Insert x into sorted s0<=s1<=s2<=s3 -> sorted out[0..4] (verified round 7+).
__device__ __forceinline__ void insert5(h2 x, h2 s0, h2 s1, h2 s2, h2 s3, h2* out) {
    out[0] = h2min(x, s0);
    out[1] = h2max(s0, h2min(x, s1));
    out[2] = h2max(s1, h2min(x, s2));
    out[3] = h2max(s2, h2min(x, s3));
    out[4] = h2max(x, s3);
}

__global__ __launch_bounds__(256) void median5_kernel(const float* __restrict__ img,
                                                      float* __restrict__ out) {
    const float INF = __builtin_inff();

    if (blockIdx.x >= NB_BND) {
        // ===== interior: 8x2 strips, shared vertical sort + packed-f16 network =====
        int gid = (blockIdx.x - NB_BND) * 256 + threadIdx.x;
        if (gid >= N_STRIPS) return;
        int xs = gid % SPR;
        int t = gid / SPR;
        int rp = t % ROWPAIRS;
        int c = t / ROWPAIRS;
        int y0 = 2 + 2 * rp;
        if (y0 > 1019) y0 = 1019;       // last pair overlaps rows 1019,1020 (dup write, same value)
        int x0 = 2 + 8 * xs;

        const float* p = img + (size_t)c * IMG_H * IMG_W;

        // V[j][r] packed {col_j, col_{j+4}} over 6 rows y0-2 .. y0+3.
        h2 V[8][6];
#pragma unroll
        for (int r = 0; r < 6; ++r) {
            const float4* rpnt = (const float4*)(p + (y0 - 2 + r) * IMG_W + (x0 - 2));
            float4 a = rpnt[0];   // c0..c3
            float4 b = rpnt[1];   // c4..c7
            float4 d = rpnt[2];   // c8..c11
            V[0][r] = pkrtz(a.x, b.x);
            V[1][r] = pkrtz(a.y, b.y);
            V[2][r] = pkrtz(a.z, b.z);
            V[3][r] = pkrtz(a.w, b.w);
            V[4][r] = pkrtz(b.x, d.x);
            V[5][r] = pkrtz(b.y, d.y);
            V[6][r] = pkrtz(b.z, d.z);
            V[7][r] = pkrtz(b.w, d.w);
        }

        // Shared middle sort: V[j][1..4] -> ascending (5-CE 4-sorter).
#pragma unroll
        for (int j = 0; j < 8; ++j) {
            CEh(V[j][1], V[j][2]); CEh(V[j][3], V[j][4]);
            CEh(V[j][1], V[j][3]); CEh(V[j][2], V[j][4]);
            CEh(V[j][2], V[j][3]);
        }

        float* po = out + (size_t)c * IMG_H * IMG_W + (size_t)y0 * IMG_W + x0;

        // Window A: rows y0-2..y0+2 (insert V[j][0]).
        {
            h2 QA[8][5];
#pragma unroll
            for (int j = 0; j < 8; ++j)
                insert5(V[j][0], V[j][1], V[j][2], V[j][3], V[j][4], QA[j]);
            strip_medians(QA, po);
        }
        // Window B: rows y0-1..y0+3 (insert V[j][5]).
        {
            h2 QB[8][5];
#pragma unroll
            for (int j = 0; j < 8; ++j)
                insert5(V[j][5], V[j][1], V[j][2], V[j][3], V[j][4], QB[j]);
            strip_medians(QB, po + IMG_W);
        }
    } else {
        // ===== boundary frame FIRST (no tail): exact fp32 bitonic-32 (verified) =====
        int gid = blockIdx.x * 256 + threadIdx.x;
        if (gid >= N_BND) return;
        int c = gid / BND_PER_C;
        int b = gid % BND_PER_C;
        int y, x;
        if (b < 2048) {                 // rows 0,1
            y = b >> 10; x = b & 1023;
        } else if (b < 5120) {          // rows 1021..1023
            int t2 = b - 2048;
            y = 1021 + (t2 >> 10); x = t2 & 1023;
        } else {                        // rows 2..1020, cols {0,1} ∪ {1018..1023}
            int t2 = b - 5120;
            y = 2 + (t2 >> 3);
            int m = t2 & 7;
            x = (m < 2) ? m : (1016 + m);
        }

        const float* p = img + (size_t)c * IMG_H * IMG_W;
        float v[32];
#pragma unroll
        for (int i = 25; i < 32; ++i) v[i] = INF;
#pragma unroll
        for (int dy = -2; dy <= 2; ++dy) {
#pragma unroll
            for (int dx = -2; dx <= 2; ++dx) {
                int yy = y + dy;
                int xx = x + dx;
                bool valid = (yy >= 0) && (yy <= IMG_H - 2) && (xx >= 0) && (xx <= IMG_W - 2);
                int yc = min(max(yy, 0), IMG_H - 1);
                int xc = min(max(xx, 0), IMG_W - 1);
                float val = p[yc * IMG_W + xc];
                v[(dy + 2) * 5 + (dx + 2)] = valid ? val : INF;
            }
        }
#pragma unroll
        for (int k = 2; k <= 32; k <<= 1) {
#pragma unroll
            for (int j = k >> 1; j > 0; j >>= 1) {
#pragma unroll
                for (int i = 0; i < 32; ++i) {
                    int l = i ^ j;
                    if (l > i) {
                        bool up = ((i & k) == 0);
                        float a = v[i];
                        float b2 = v[l];
                        float mn = fminf(a, b2);
                        float mx = fmaxf(a, b2);
                        v[i] = up ? mn : mx;
                        v[l] = up ? mx : mn;
                    }
                }
            }
        }
        int ny = min(y + 2, IMG_H - 2) - max(y - 2, 0) + 1;
        int nx = min(x + 2, IMG_W - 2) - max(x - 2, 0) + 1;
        int n = ny * nx;
        int ilo = (n - 1) >> 1;
        int ihi = n >> 1;
        float lo = 0.0f, hi = 0.0f;
#pragma unroll
        for (int i = 0; i < 13; ++i) {
            if (i == ilo) lo = v[i];
            if (i == ihi) hi = v[i];
        }
        out[(size_t)c * IMG_H * IMG_W + (size_t)y * IMG_W + x] = 0.5f * (lo + hi);
    }
}

extern "C" void kernel_launch(void* const* d_in, const int* in_sizes, int n_in,
                              void* d_out, int out_size, void* d_ws, size_t ws_size,
                              hipStream_t stream) {
    const float* img = (const float*)d_in[0];
    float* out = (float*)d_out;
    dim3 block(256);
    dim3 grid(NB_BND + NB_INT);
    median5_kernel<<<grid, block, 0, stream>>>(img, out);
}